// Round 7
// baseline (534.185 us; speedup 1.0000x reference)
//
#include <hip/hip_runtime.h>
#include <hip/hip_bf16.h>
#include <stdint.h>

#define B_   4
#define S_   2048
#define DIN  1024
#define EMB  1024
#define H_   16
#define HD_  64
#define TOK  (B_*S_)            // 8192
#define NQKV 3072

using bf16  = __hip_bfloat16;
using f32x4 = __attribute__((ext_vector_type(4))) float;
using f32x16 = __attribute__((ext_vector_type(16))) float;
using s16x8 = __attribute__((ext_vector_type(8))) short;
using bf16x8 = __attribute__((ext_vector_type(8))) __bf16;

__device__ __forceinline__ f32x4 mfma16(s16x8 a, s16x8 b, f32x4 c) {
  return __builtin_amdgcn_mfma_f32_16x16x32_bf16(
      __builtin_bit_cast(bf16x8, a), __builtin_bit_cast(bf16x8, b), c, 0, 0, 0);
}
__device__ __forceinline__ f32x16 mfma32(s16x8 a, s16x8 b, f32x16 c) {
  return __builtin_amdgcn_mfma_f32_32x32x16_bf16(
      __builtin_bit_cast(bf16x8, a), __builtin_bit_cast(bf16x8, b), c, 0, 0, 0);
}

__device__ __forceinline__ void gload_lds16(const void* g, void* l) {
  __builtin_amdgcn_global_load_lds(
      (const __attribute__((address_space(1))) uint32_t*)g,
      (__attribute__((address_space(3))) uint32_t*)l, 16, 0, 0);
}

// pack two f32 -> one u32 of 2 bf16 (lo,hi)
__device__ __forceinline__ uint32_t cvtpk_bf16(float lo, float hi) {
  uint32_t r;
  asm("v_cvt_pk_bf16_f32 %0, %1, %2" : "=v"(r) : "v"(lo), "v"(hi));
  return r;
}
// exchange a's lanes 32-63 with b's lanes 0-31
__device__ __forceinline__ void plswap32(uint32_t &a, uint32_t &b) {
  asm("v_permlane32_swap_b32 %0, %1" : "+v"(a), "+v"(b));
}

union U8 { s16x8 v; bf16 b[8]; };
union PaU { uint32_t w[4]; s16x8 v; };

// ---------------------------------------------------------------- f32 -> bf16
// Merged: one kernel converts x (4096 blocks), W_qkv (1536), W_out (512).
__global__ __launch_bounds__(256) void cvt_all(const float* __restrict__ x,
                                               const float* __restrict__ wqkv,
                                               const float* __restrict__ wout,
                                               bf16* __restrict__ xb,
                                               bf16* __restrict__ wqkvb,
                                               bf16* __restrict__ woutb) {
  int b = blockIdx.x;
  const float* in; bf16* out; int base;
  if (b < 4096)      { in = x;    out = xb;    base = b; }
  else if (b < 5632) { in = wqkv; out = wqkvb; base = b - 4096; }
  else               { in = wout; out = woutb; base = b - 5632; }
  int i = (base * 256 + (int)threadIdx.x) * 8;
  float4 a = *(const float4*)(in + i);
  float4 c = *(const float4*)(in + i + 4);
  U8 u;
  u.b[0] = __float2bfloat16(a.x); u.b[1] = __float2bfloat16(a.y);
  u.b[2] = __float2bfloat16(a.z); u.b[3] = __float2bfloat16(a.w);
  u.b[4] = __float2bfloat16(c.x); u.b[5] = __float2bfloat16(c.y);
  u.b[6] = __float2bfloat16(c.z); u.b[7] = __float2bfloat16(c.w);
  *(s16x8*)(out + i) = u.v;
}

// ---------------------------------------------------------------- GEMM (TN)
// (unchanged — passed rounds 3-5)
template<int MODE>
__global__ __launch_bounds__(256) void gemm_bt(
    const bf16* __restrict__ A, const bf16* __restrict__ Bw,
    const float* __restrict__ bias,
    bf16* __restrict__ outQK, bf16* __restrict__ outV,
    float* __restrict__ outF, int N, int K)
{
  const int tid  = threadIdx.x;
  const int lane = tid & 63;
  const int w    = tid >> 6;
  const int wm   = w >> 1, wn = w & 1;
  const int bn0  = blockIdx.x * 128;
  const int bm0  = blockIdx.y * 128;

  __shared__ __align__(16) bf16 As[128 * 64];
  __shared__ __align__(16) bf16 Bs[128 * 64];

  f32x4 acc[4][4];
  const f32x4 zero = {0.f, 0.f, 0.f, 0.f};
  for (int mt = 0; mt < 4; ++mt)
    for (int nt = 0; nt < 4; ++nt) acc[mt][nt] = zero;

  for (int kt = 0; kt < K; kt += 64) {
    for (int i = 0; i < 4; ++i) {
      int c   = i * 256 + tid;
      int row = c >> 3, p = c & 7;
      int sc  = p ^ (row & 7);
      gload_lds16(A + (size_t)(bm0 + row) * K + kt + sc * 8, (char*)As + c * 16);
      gload_lds16(Bw + (size_t)(bn0 + row) * K + kt + sc * 8, (char*)Bs + c * 16);
    }
    __syncthreads();

    s16x8 af[4][2], bfr[4][2];
    for (int mt = 0; mt < 4; ++mt)
      for (int kk = 0; kk < 2; ++kk) {
        int row  = wm * 64 + mt * 16 + (lane & 15);
        int byte = row * 128 + (((kk * 4 + (lane >> 4)) ^ (row & 7)) << 4);
        af[mt][kk] = *(const s16x8*)((const char*)As + byte);
      }
    for (int nt = 0; nt < 4; ++nt)
      for (int kk = 0; kk < 2; ++kk) {
        int row  = wn * 64 + nt * 16 + (lane & 15);
        int byte = row * 128 + (((kk * 4 + (lane >> 4)) ^ (row & 7)) << 4);
        bfr[nt][kk] = *(const s16x8*)((const char*)Bs + byte);
      }
    for (int kk = 0; kk < 2; ++kk)
      for (int mt = 0; mt < 4; ++mt)
        for (int nt = 0; nt < 4; ++nt)
          acc[mt][nt] = mfma16(af[mt][kk], bfr[nt][kk], acc[mt][nt]);
    __syncthreads();
  }

  const int col_l = lane & 15;
  const int rgrp  = lane >> 4;
  for (int mt = 0; mt < 4; ++mt)
    for (int nt = 0; nt < 4; ++nt) {
      int n0  = bn0 + wn * 64 + nt * 16;
      int col = n0 + col_l;
      float bv = bias[col];
      if (MODE == 0) {
        int h = col / 192, rem = col % 192;
        int cc = rem / 64, d = rem % 64;
        for (int r = 0; r < 4; ++r) {
          int row = bm0 + wm * 64 + mt * 16 + rgrp * 4 + r;
          bf16 bvv = __float2bfloat16(acc[mt][nt][r] + bv);
          if (cc == 2) {
            int bb = row >> 11, s = row & 2047;
            outV[(((size_t)bb * H_ + h) * HD_ + d) * S_ + s] = bvv;   // V^T
          } else {
            outQK[(size_t)row * NQKV + col] = bvv;
          }
        }
      } else {
        for (int r = 0; r < 4; ++r) {
          int row = bm0 + wm * 64 + mt * 16 + rgrp * 4 + r;
          outF[(size_t)row * EMB + col] = acc[mt][nt][r] + bv;
        }
      }
    }
}

// ---------------------------------------------------------------- attention v4
// Swapped-operand 32x32x16 flash attention, softmax in registers.
// Round-6 changes vs v3:
//  * KVBLK=128 (LDS 64KB, still 2 blocks/CU): 4 independent QK MFMA chains
//    (pA..pD) for ILP; barriers/branches/pmax-shuffles halved per kv.
//  * __launch_bounds__(512,4): VGPR cap 128 (was 80 chosen) so the compiler
//    can hoist the loop-invariant swizzled ds_read addresses. Grid already
//    caps occupancy at 4 waves/SIMD, so no occupancy loss.
__global__ __launch_bounds__(512, 4) void attn2(const bf16* __restrict__ qkvb,
                                                const bf16* __restrict__ vb,
                                                bf16* __restrict__ ob)
{
  const int tid = threadIdx.x, lane = tid & 63, w = tid >> 6;  // w 0..7
  const int hi = lane >> 5, l31 = lane & 31;
  const int f  = blockIdx.x;                       // 0..511
  const int bh = (f & 7) | (((f >> 6) & 7) << 3);  // XCD = f&7 pins bh to one XCD
  const int qt = (f >> 3) & 7;
  const int bb = bh >> 4, h = bh & 15;
  const int q0 = qt * 256;
  const size_t tokbase = (size_t)bb * S_;

  __shared__ __align__(16) bf16 Ks[2][128 * 64];   // [kv][k]   rows 128B
  __shared__ __align__(16) bf16 Vts[2][64 * 128];  // [d][kv]   rows 256B

  // Q fragments (B-operand: col=l31=q, k=16*ks+8*hi+e), scaled 0.125*log2e
  s16x8 qf[4];
  {
    const int qrow = q0 + w * 32 + l31;
    const bf16* qp = qkvb + (tokbase + qrow) * NQKV + h * 192 + hi * 8;
    #pragma unroll
    for (int ks = 0; ks < 4; ++ks) {
      U8 u; u.v = *(const s16x8*)(qp + ks * 16);
      #pragma unroll
      for (int j = 0; j < 8; ++j)
        u.b[j] = __float2bfloat16(__bfloat162float(u.b[j]) * 0.18033688011112042f);
      qf[ks] = u.v;
    }
  }

  f32x16 zero16;
  #pragma unroll
  for (int i = 0; i < 16; ++i) zero16[i] = 0.f;
  f32x16 oA = zero16, oB = zero16;   // C-layout: col=d(=l31/+32), row=q pattern
  f32x16 nm16 = zero16;              // all elems = -m (m starts at 0)
  float l0 = 0.f;

  const bf16* Kbase = qkvb + tokbase * NQKV + h * 192 + 64;
  const bf16* Vbase = vb + (size_t)bh * HD_ * S_;

  auto STAGE = [&](int b, int t) {
    const int kv0 = t * 128;
    #pragma unroll
    for (int i = 0; i < 2; ++i) {          // K: [128][64], 1024 chunks
      int c = i * 512 + tid;
      int row = c >> 3, p = c & 7, sc = p ^ (row & 7);
      gload_lds16(Kbase + (size_t)(kv0 + row) * NQKV + sc * 8,
                  (char*)Ks[b] + c * 16);
    }
    #pragma unroll
    for (int i = 0; i < 2; ++i) {          // V^T: [64][128], 1024 chunks
      int c = i * 512 + tid;
      int row = c >> 4, p = c & 15, sc = p ^ (row & 7);
      gload_lds16(Vbase + (size_t)row * S_ + kv0 + sc * 8,
                  (char*)Vts[b] + c * 16);
    }
  };

  STAGE(0, 0);
  __syncthreads();

  int cur = 0;
  for (int t = 0; t < S_ / 128; ++t) {
    if (t < S_ / 128 - 1) STAGE(cur ^ 1, t + 1);   // issue-early

    // ---- S^T - m = K · Q^T + (-m); 4 independent chains (kv 0..127)
    f32x16 pA, pB, pC, pD;
    #pragma unroll
    for (int ks = 0; ks < 4; ++ks) {
      {
        int arow = l31;
        int byte = arow * 128 + (((2 * ks + hi) ^ (arow & 7)) << 4);
        s16x8 kf = *(const s16x8*)((const char*)Ks[cur] + byte);
        pA = mfma32(kf, qf[ks], ks == 0 ? nm16 : pA);
      }
      {
        int arow = 32 + l31;
        int byte = arow * 128 + (((2 * ks + hi) ^ (arow & 7)) << 4);
        s16x8 kf = *(const s16x8*)((const char*)Ks[cur] + byte);
        pB = mfma32(kf, qf[ks], ks == 0 ? nm16 : pB);
      }
      {
        int arow = 64 + l31;
        int byte = arow * 128 + (((2 * ks + hi) ^ (arow & 7)) << 4);
        s16x8 kf = *(const s16x8*)((const char*)Ks[cur] + byte);
        pC = mfma32(kf, qf[ks], ks == 0 ? nm16 : pC);
      }
      {
        int arow = 96 + l31;
        int byte = arow * 128 + (((2 * ks + hi) ^ (arow & 7)) << 4);
        s16x8 kf = *(const s16x8*)((const char*)Ks[cur] + byte);
        pD = mfma32(kf, qf[ks], ks == 0 ? nm16 : pD);
      }
    }

    // ---- row max of (S-m): in-lane tree + partner combine
    float mx8[8];
    #pragma unroll
    for (int i = 0; i < 8; ++i)
      mx8[i] = fmaxf(fmaxf(fmaxf(pA[i], pA[i + 8]), fmaxf(pB[i], pB[i + 8])),
                     fmaxf(fmaxf(pC[i], pC[i + 8]), fmaxf(pD[i], pD[i + 8])));
    float pmax = fmaxf(fmaxf(fmaxf(mx8[0], mx8[4]), fmaxf(mx8[1], mx8[5])),
                       fmaxf(fmaxf(mx8[2], mx8[6]), fmaxf(mx8[3], mx8[7])));
    pmax = fmaxf(pmax, __shfl_xor(pmax, 32));

    // ---- defer-max rescale (rare); everything already in S-m domain
    if (__any(pmax > 11.0f)) {
      float al = __builtin_amdgcn_exp2f(-pmax);
      l0 *= al;
      #pragma unroll
      for (int r = 0; r < 16; ++r) {
        float alr = __shfl(al, (r & 3) + 8 * (r >> 2) + 4 * hi);
        oA[r] *= alr; oB[r] *= alr;
      }
      #pragma unroll
      for (int r = 0; r < 16; ++r) {
        pA[r] -= pmax; pB[r] -= pmax; pC[r] -= pmax; pD[r] -= pmax;
      }
      #pragma unroll
      for (int i = 0; i < 16; ++i) nm16[i] -= pmax;
    }

    // ---- exp2 (args <= 11 guaranteed) + partial row-sum
    #pragma unroll
    for (int r = 0; r < 16; ++r) {
      pA[r] = __builtin_amdgcn_exp2f(pA[r]);
      pB[r] = __builtin_amdgcn_exp2f(pB[r]);
      pC[r] = __builtin_amdgcn_exp2f(pC[r]);
      pD[r] = __builtin_amdgcn_exp2f(pD[r]);
    }
    float s8[8];
    #pragma unroll
    for (int i = 0; i < 8; ++i)
      s8[i] = ((pA[i] + pA[i + 8]) + (pB[i] + pB[i + 8])) +
              ((pC[i] + pC[i + 8]) + (pD[i] + pD[i + 8]));
    l0 += ((s8[0] + s8[1]) + (s8[2] + s8[3])) +
          ((s8[4] + s8[5]) + (s8[6] + s8[7]));

    // ---- pack P (cvt_pk + permlane32_swap) and PV, per 16-kv step
    #pragma unroll
    for (int h2 = 0; h2 < 2; ++h2) {
      #pragma unroll
      for (int s = 0; s < 4; ++s) {
        const int sub = s & 1;
        const f32x16 &ph = h2 ? ((s < 2) ? pC : pD) : ((s < 2) ? pA : pB);
        uint32_t L0 = cvtpk_bf16(ph[8 * sub + 0], ph[8 * sub + 1]);
        uint32_t L1 = cvtpk_bf16(ph[8 * sub + 2], ph[8 * sub + 3]);
        uint32_t H0 = cvtpk_bf16(ph[8 * sub + 4], ph[8 * sub + 5]);
        uint32_t H1 = cvtpk_bf16(ph[8 * sub + 6], ph[8 * sub + 7]);
        plswap32(L0, H0);
        plswap32(L1, H1);
        PaU pa; pa.w[0] = L0; pa.w[1] = L1; pa.w[2] = H0; pa.w[3] = H1;
        const int ch = 8 * h2 + 2 * s + hi;       // kv 16B-chunk index 0..15
        {
          int vrow = l31;
          int byte = vrow * 256 + ((ch ^ (vrow & 7)) << 4);
          s16x8 vf = *(const s16x8*)((const char*)Vts[cur] + byte);
          oA = mfma32(pa.v, vf, oA);
        }
        {
          int vrow = 32 + l31;
          int byte = vrow * 256 + ((ch ^ (vrow & 7)) << 4);
          s16x8 vf = *(const s16x8*)((const char*)Vts[cur] + byte);
          oB = mfma32(pa.v, vf, oB);
        }
      }
    }
    __syncthreads();   // one vmcnt(0)+barrier per 128-kv tile
    cur ^= 1;
  }

  // ---- epilogue: combine partner l0, normalize, write
  float l0t = l0 + __shfl_xor(l0, 32);
  float inv = 1.0f / l0t;                  // lane's q = l31
  #pragma unroll
  for (int r = 0; r < 16; ++r) {
    int q = (r & 3) + 8 * (r >> 2) + 4 * hi;
    float invr = __shfl(inv, q);
    int qrow = q0 + w * 32 + q;
    bf16* op = ob + (tokbase + qrow) * EMB + h * 64 + l31;
    op[0]  = __float2bfloat16(oA[r] * invr);
    op[32] = __float2bfloat16(oB[r] * invr);
  }
}

// ---------------------------------------------------------------- launcher
// Workspace map (ob aliases xb — xb dead after gemm0, rewritten every replay):
//   [0,16MB) xb->ob  [16,22) wqkvb  [22,24) woutb  [24,72) qkvb  [72,88) vb
extern "C" void kernel_launch(void* const* d_in, const int* in_sizes, int n_in,
                              void* d_out, int out_size, void* d_ws, size_t ws_size,
                              hipStream_t stream) {
  const float* x    = (const float*)d_in[0];
  const float* Wqkv = (const float*)d_in[1];
  const float* bqkv = (const float*)d_in[2];
  const float* Wout = (const float*)d_in[3];
  const float* bout = (const float*)d_in[4];
  float* out = (float*)d_out;

  char* ws = (char*)d_ws;
  bf16* xb    = (bf16*)(ws);
  bf16* wqkvb = (bf16*)(ws + 16777216);
  bf16* woutb = (bf16*)(ws + 23068672);
  bf16* qkvb  = (bf16*)(ws + 25165824);
  bf16* vb    = (bf16*)(ws + 75497472);
  bf16* ob    = xb;

  cvt_all<<<dim3(6144), 256, 0, stream>>>(x, Wqkv, Wout, xb, wqkvb, woutb);

  gemm_bt<0><<<dim3(NQKV / 128, TOK / 128), 256, 0, stream>>>(
      xb, wqkvb, bqkv, qkvb, vb, nullptr, NQKV, DIN);

  attn2<<<dim3(512), 512, 0, stream>>>(qkvb, vb, ob);

  gemm_bt<1><<<dim3(EMB / 128, TOK / 128), 256, 0, stream>>>(
      ob, woutb, bout, nullptr, nullptr, out, EMB, EMB);
}

// Round 8
// 217.251 us; speedup vs baseline: 2.4588x; 2.4588x over previous
//
#include <hip/hip_runtime.h>
#include <hip/hip_bf16.h>
#include <stdint.h>

#define B_   4
#define S_   2048
#define DIN  1024
#define EMB  1024
#define H_   16
#define HD_  64
#define TOK  (B_*S_)            // 8192
#define NQKV 3072

using bf16  = __hip_bfloat16;
using f32x4 = __attribute__((ext_vector_type(4))) float;
using f32x16 = __attribute__((ext_vector_type(16))) float;
using s16x8 = __attribute__((ext_vector_type(8))) short;
using bf16x8 = __attribute__((ext_vector_type(8))) __bf16;

__device__ __forceinline__ f32x4 mfma16(s16x8 a, s16x8 b, f32x4 c) {
  return __builtin_amdgcn_mfma_f32_16x16x32_bf16(
      __builtin_bit_cast(bf16x8, a), __builtin_bit_cast(bf16x8, b), c, 0, 0, 0);
}
__device__ __forceinline__ f32x16 mfma32(s16x8 a, s16x8 b, f32x16 c) {
  return __builtin_amdgcn_mfma_f32_32x32x16_bf16(
      __builtin_bit_cast(bf16x8, a), __builtin_bit_cast(bf16x8, b), c, 0, 0, 0);
}

__device__ __forceinline__ void gload_lds16(const void* g, void* l) {
  __builtin_amdgcn_global_load_lds(
      (const __attribute__((address_space(1))) uint32_t*)g,
      (__attribute__((address_space(3))) uint32_t*)l, 16, 0, 0);
}

// pack two f32 -> one u32 of 2 bf16 (lo,hi)
__device__ __forceinline__ uint32_t cvtpk_bf16(float lo, float hi) {
  uint32_t r;
  asm("v_cvt_pk_bf16_f32 %0, %1, %2" : "=v"(r) : "v"(lo), "v"(hi));
  return r;
}
// exchange a's lanes 32-63 with b's lanes 0-31
__device__ __forceinline__ void plswap32(uint32_t &a, uint32_t &b) {
  asm("v_permlane32_swap_b32 %0, %1" : "+v"(a), "+v"(b));
}

union U8 { s16x8 v; bf16 b[8]; };
union PaU { uint32_t w[4]; s16x8 v; };

// ---------------------------------------------------------------- f32 -> bf16
// Merged: one kernel converts x (4096 blocks), W_qkv (1536), W_out (512).
__global__ __launch_bounds__(256) void cvt_all(const float* __restrict__ x,
                                               const float* __restrict__ wqkv,
                                               const float* __restrict__ wout,
                                               bf16* __restrict__ xb,
                                               bf16* __restrict__ wqkvb,
                                               bf16* __restrict__ woutb) {
  int b = blockIdx.x;
  const float* in; bf16* out; int base;
  if (b < 4096)      { in = x;    out = xb;    base = b; }
  else if (b < 5632) { in = wqkv; out = wqkvb; base = b - 4096; }
  else               { in = wout; out = woutb; base = b - 5632; }
  int i = (base * 256 + (int)threadIdx.x) * 8;
  float4 a = *(const float4*)(in + i);
  float4 c = *(const float4*)(in + i + 4);
  U8 u;
  u.b[0] = __float2bfloat16(a.x); u.b[1] = __float2bfloat16(a.y);
  u.b[2] = __float2bfloat16(a.z); u.b[3] = __float2bfloat16(a.w);
  u.b[4] = __float2bfloat16(c.x); u.b[5] = __float2bfloat16(c.y);
  u.b[6] = __float2bfloat16(c.z); u.b[7] = __float2bfloat16(c.w);
  *(s16x8*)(out + i) = u.v;
}

// ---------------------------------------------------------------- GEMM (TN)
// (unchanged — passed rounds 3-7)
template<int MODE>
__global__ __launch_bounds__(256) void gemm_bt(
    const bf16* __restrict__ A, const bf16* __restrict__ Bw,
    const float* __restrict__ bias,
    bf16* __restrict__ outQK, bf16* __restrict__ outV,
    float* __restrict__ outF, int N, int K)
{
  const int tid  = threadIdx.x;
  const int lane = tid & 63;
  const int w    = tid >> 6;
  const int wm   = w >> 1, wn = w & 1;
  const int bn0  = blockIdx.x * 128;
  const int bm0  = blockIdx.y * 128;

  __shared__ __align__(16) bf16 As[128 * 64];
  __shared__ __align__(16) bf16 Bs[128 * 64];

  f32x4 acc[4][4];
  const f32x4 zero = {0.f, 0.f, 0.f, 0.f};
  for (int mt = 0; mt < 4; ++mt)
    for (int nt = 0; nt < 4; ++nt) acc[mt][nt] = zero;

  for (int kt = 0; kt < K; kt += 64) {
    for (int i = 0; i < 4; ++i) {
      int c   = i * 256 + tid;
      int row = c >> 3, p = c & 7;
      int sc  = p ^ (row & 7);
      gload_lds16(A + (size_t)(bm0 + row) * K + kt + sc * 8, (char*)As + c * 16);
      gload_lds16(Bw + (size_t)(bn0 + row) * K + kt + sc * 8, (char*)Bs + c * 16);
    }
    __syncthreads();

    s16x8 af[4][2], bfr[4][2];
    for (int mt = 0; mt < 4; ++mt)
      for (int kk = 0; kk < 2; ++kk) {
        int row  = wm * 64 + mt * 16 + (lane & 15);
        int byte = row * 128 + (((kk * 4 + (lane >> 4)) ^ (row & 7)) << 4);
        af[mt][kk] = *(const s16x8*)((const char*)As + byte);
      }
    for (int nt = 0; nt < 4; ++nt)
      for (int kk = 0; kk < 2; ++kk) {
        int row  = wn * 64 + nt * 16 + (lane & 15);
        int byte = row * 128 + (((kk * 4 + (lane >> 4)) ^ (row & 7)) << 4);
        bfr[nt][kk] = *(const s16x8*)((const char*)Bs + byte);
      }
    for (int kk = 0; kk < 2; ++kk)
      for (int mt = 0; mt < 4; ++mt)
        for (int nt = 0; nt < 4; ++nt)
          acc[mt][nt] = mfma16(af[mt][kk], bfr[nt][kk], acc[mt][nt]);
    __syncthreads();
  }

  const int col_l = lane & 15;
  const int rgrp  = lane >> 4;
  for (int mt = 0; mt < 4; ++mt)
    for (int nt = 0; nt < 4; ++nt) {
      int n0  = bn0 + wn * 64 + nt * 16;
      int col = n0 + col_l;
      float bv = bias[col];
      if (MODE == 0) {
        int h = col / 192, rem = col % 192;
        int cc = rem / 64, d = rem % 64;
        for (int r = 0; r < 4; ++r) {
          int row = bm0 + wm * 64 + mt * 16 + rgrp * 4 + r;
          bf16 bvv = __float2bfloat16(acc[mt][nt][r] + bv);
          if (cc == 2) {
            int bb = row >> 11, s = row & 2047;
            outV[(((size_t)bb * H_ + h) * HD_ + d) * S_ + s] = bvv;   // V^T
          } else {
            outQK[(size_t)row * NQKV + col] = bvv;
          }
        }
      } else {
        for (int r = 0; r < 4; ++r) {
          int row = bm0 + wm * 64 + mt * 16 + rgrp * 4 + r;
          outF[(size_t)row * EMB + col] = acc[mt][nt][r] + bv;
        }
      }
    }
}

// ---------------------------------------------------------------- attention v5
// = round-5 v3 structure (KVBLK=64, 2 P-chains — known-good 108 µs) with a
// SAFE register-cap raise. Round-7 lesson: __launch_bounds__(512,4) produced
// a 64-VGPR cap (this hipcc treats arg2 as min BLOCKS/CU: 4 blk x 8 waves =
// 32 waves/CU = 8/SIMD -> 64 cap) and v4's ~128-reg state spilled to scratch
// (2 GB/dispatch traffic, 450 µs). (512,2) is safe under BOTH readings:
// blocks/CU -> 16 waves/CU -> cap 128; waves/EU -> cap 256. v3 state ~116
// regs fits at 128, giving the compiler room to hoist the 16 loop-invariant
// swizzled LDS addresses (R5 diagnosis: they were rematerialized every iter
// at the natural 80-reg allocation).
__global__ __launch_bounds__(512, 2) void attn2(const bf16* __restrict__ qkvb,
                                                const bf16* __restrict__ vb,
                                                bf16* __restrict__ ob)
{
  const int tid = threadIdx.x, lane = tid & 63, w = tid >> 6;  // w 0..7
  const int hi = lane >> 5, l31 = lane & 31;
  const int f  = blockIdx.x;                       // 0..511
  const int bh = (f & 7) | (((f >> 6) & 7) << 3);  // XCD = f&7 pins bh to one XCD
  const int qt = (f >> 3) & 7;
  const int bb = bh >> 4, h = bh & 15;
  const int q0 = qt * 256;
  const size_t tokbase = (size_t)bb * S_;

  __shared__ __align__(16) bf16 Ks[2][64 * 64];
  __shared__ __align__(16) bf16 Vts[2][64 * 64];   // V^T [d][kv]

  // Q fragments (B-operand: col=l31=q, k=16*ks+8*hi+e), scaled 0.125*log2e
  s16x8 qf[4];
  {
    const int qrow = q0 + w * 32 + l31;
    const bf16* qp = qkvb + (tokbase + qrow) * NQKV + h * 192 + hi * 8;
    #pragma unroll
    for (int ks = 0; ks < 4; ++ks) {
      U8 u; u.v = *(const s16x8*)(qp + ks * 16);
      #pragma unroll
      for (int j = 0; j < 8; ++j)
        u.b[j] = __float2bfloat16(__bfloat162float(u.b[j]) * 0.18033688011112042f);
      qf[ks] = u.v;
    }
  }

  f32x16 zero16;
  #pragma unroll
  for (int i = 0; i < 16; ++i) zero16[i] = 0.f;
  f32x16 oA = zero16, oB = zero16;   // C-layout: col=d(=l31/+32), row=q pattern
  f32x16 nm16 = zero16;              // all elems = -m (m starts at 0)
  float l0 = 0.f;

  const bf16* Kbase = qkvb + tokbase * NQKV + h * 192 + 64;
  const bf16* Vbase = vb + (size_t)bh * HD_ * S_;

  auto STAGE = [&](int b, int t) {
    const int kv0 = t * 64;
    const int c = tid;                       // 512 thr = 512 chunks per array
    const int row = c >> 3, p = c & 7, sc = p ^ (row & 7);
    gload_lds16(Kbase + (size_t)(kv0 + row) * NQKV + sc * 8,
                (char*)Ks[b] + c * 16);
    gload_lds16(Vbase + (size_t)row * S_ + kv0 + sc * 8,
                (char*)Vts[b] + c * 16);
  };

  STAGE(0, 0);
  __syncthreads();

  int cur = 0;
  for (int t = 0; t < S_ / 64; ++t) {
    if (t < S_ / 64 - 1) STAGE(cur ^ 1, t + 1);   // issue-early

    // ---- S^T - m = K · Q^T + (-m)   (lane: q=l31; kv in-register)
    f32x16 pA, pB;
    #pragma unroll
    for (int ks = 0; ks < 4; ++ks) {
      {
        int arow = l31;
        int byte = arow * 128 + (((2 * ks + hi) ^ (arow & 7)) << 4);
        s16x8 kf = *(const s16x8*)((const char*)Ks[cur] + byte);
        pA = mfma32(kf, qf[ks], ks == 0 ? nm16 : pA);
      }
      {
        int arow = 32 + l31;
        int byte = arow * 128 + (((2 * ks + hi) ^ (arow & 7)) << 4);
        s16x8 kf = *(const s16x8*)((const char*)Ks[cur] + byte);
        pB = mfma32(kf, qf[ks], ks == 0 ? nm16 : pB);
      }
    }

    // ---- row max of (S-m): in-lane tree + partner combine
    float mx8[8];
    #pragma unroll
    for (int i = 0; i < 8; ++i)
      mx8[i] = fmaxf(fmaxf(pA[i], pA[i + 8]), fmaxf(pB[i], pB[i + 8]));
    float pmax = fmaxf(fmaxf(fmaxf(mx8[0], mx8[4]), fmaxf(mx8[1], mx8[5])),
                       fmaxf(fmaxf(mx8[2], mx8[6]), fmaxf(mx8[3], mx8[7])));
    pmax = fmaxf(pmax, __shfl_xor(pmax, 32));

    // ---- defer-max rescale (rare); everything already in S-m domain
    if (__any(pmax > 11.0f)) {
      float al = __builtin_amdgcn_exp2f(-pmax);
      l0 *= al;
      #pragma unroll
      for (int r = 0; r < 16; ++r) {
        float alr = __shfl(al, (r & 3) + 8 * (r >> 2) + 4 * hi);
        oA[r] *= alr; oB[r] *= alr;
      }
      #pragma unroll
      for (int r = 0; r < 16; ++r) { pA[r] -= pmax; pB[r] -= pmax; }
      #pragma unroll
      for (int i = 0; i < 16; ++i) nm16[i] -= pmax;
    }

    // ---- exp2 (args <= 11 guaranteed) + partial row-sum
    #pragma unroll
    for (int r = 0; r < 16; ++r) {
      pA[r] = __builtin_amdgcn_exp2f(pA[r]);
      pB[r] = __builtin_amdgcn_exp2f(pB[r]);
    }
    float s8[8];
    #pragma unroll
    for (int i = 0; i < 8; ++i)
      s8[i] = (pA[i] + pA[i + 8]) + (pB[i] + pB[i + 8]);
    l0 += ((s8[0] + s8[1]) + (s8[2] + s8[3])) +
          ((s8[4] + s8[5]) + (s8[6] + s8[7]));

    // ---- pack P (cvt_pk + permlane32_swap) and PV per 16-kv step
    #pragma unroll
    for (int s = 0; s < 4; ++s) {
      const int sub = s & 1;
      const f32x16 &ph = (s < 2) ? pA : pB;
      uint32_t L0 = cvtpk_bf16(ph[8 * sub + 0], ph[8 * sub + 1]);
      uint32_t L1 = cvtpk_bf16(ph[8 * sub + 2], ph[8 * sub + 3]);
      uint32_t H0 = cvtpk_bf16(ph[8 * sub + 4], ph[8 * sub + 5]);
      uint32_t H1 = cvtpk_bf16(ph[8 * sub + 6], ph[8 * sub + 7]);
      plswap32(L0, H0);
      plswap32(L1, H1);
      PaU pa; pa.w[0] = L0; pa.w[1] = L1; pa.w[2] = H0; pa.w[3] = H1;
      {
        int vrow = l31;
        int byte = vrow * 128 + (((2 * s + hi) ^ (vrow & 7)) << 4);
        s16x8 vf = *(const s16x8*)((const char*)Vts[cur] + byte);
        oA = mfma32(pa.v, vf, oA);
      }
      {
        int vrow = 32 + l31;
        int byte = vrow * 128 + (((2 * s + hi) ^ (vrow & 7)) << 4);
        s16x8 vf = *(const s16x8*)((const char*)Vts[cur] + byte);
        oB = mfma32(pa.v, vf, oB);
      }
    }
    __syncthreads();   // one vmcnt(0)+barrier per tile
    cur ^= 1;
  }

  // ---- epilogue: combine partner l0, normalize, write
  float l0t = l0 + __shfl_xor(l0, 32);
  float inv = 1.0f / l0t;                  // lane's q = l31
  #pragma unroll
  for (int r = 0; r < 16; ++r) {
    int q = (r & 3) + 8 * (r >> 2) + 4 * hi;
    float invr = __shfl(inv, q);
    int qrow = q0 + w * 32 + q;
    bf16* op = ob + (tokbase + qrow) * EMB + h * 64 + l31;
    op[0]  = __float2bfloat16(oA[r] * invr);
    op[32] = __float2bfloat16(oB[r] * invr);
  }
}

// ---------------------------------------------------------------- launcher
// Workspace map (ob aliases xb — xb dead after gemm0, rewritten every replay):
//   [0,16MB) xb->ob  [16,22) wqkvb  [22,24) woutb  [24,72) qkvb  [72,88) vb
extern "C" void kernel_launch(void* const* d_in, const int* in_sizes, int n_in,
                              void* d_out, int out_size, void* d_ws, size_t ws_size,
                              hipStream_t stream) {
  const float* x    = (const float*)d_in[0];
  const float* Wqkv = (const float*)d_in[1];
  const float* bqkv = (const float*)d_in[2];
  const float* Wout = (const float*)d_in[3];
  const float* bout = (const float*)d_in[4];
  float* out = (float*)d_out;

  char* ws = (char*)d_ws;
  bf16* xb    = (bf16*)(ws);
  bf16* wqkvb = (bf16*)(ws + 16777216);
  bf16* woutb = (bf16*)(ws + 23068672);
  bf16* qkvb  = (bf16*)(ws + 25165824);
  bf16* vb    = (bf16*)(ws + 75497472);
  bf16* ob    = xb;

  cvt_all<<<dim3(6144), 256, 0, stream>>>(x, Wqkv, Wout, xb, wqkvb, woutb);

  gemm_bt<0><<<dim3(NQKV / 128, TOK / 128), 256, 0, stream>>>(
      xb, wqkvb, bqkv, qkvb, vb, nullptr, NQKV, DIN);

  attn2<<<dim3(512), 512, 0, stream>>>(qkvb, vb, ob);

  gemm_bt<1><<<dim3(EMB / 128, TOK / 128), 256, 0, stream>>>(
      ob, woutb, bout, nullptr, nullptr, out, EMB, EMB);
}